// Round 11
// baseline (207.707 us; speedup 1.0000x reference)
//
#include <hip/hip_runtime.h>
#include <hip/hip_bf16.h>

#define HH   56
#define WW_  56
#define CIN  128
#define OCH  256
#define NPIX (32*56*56)          // 100352
#define NX   (NPIX*CIN)
#define NW   (OCH*9*CIN)
#define XB_BYTES ((size_t)NX*2)  // 25690112
#define WB_BYTES ((size_t)NW*2)  // 589824
#define ZP_OFF   (XB_BYTES + WB_BYTES)
#define WS_NEEDED (ZP_OFF + 256)

#define NT   18                  // K-tiles of 64 (K = 1152)
#define SLOT 65536               // A 32KB + B 32KB per K-tile (BM=BN=256)
#define THREADS 512

typedef __attribute__((ext_vector_type(8))) short bf16x8;
typedef __attribute__((ext_vector_type(4))) float f32x4;
typedef __attribute__((address_space(1))) void v_g;
typedef __attribute__((address_space(3))) void v_l;

__device__ __forceinline__ unsigned short f2bf(float f) {
  union { float f; unsigned u; } v; v.f = f;
  unsigned r = v.u + 0x7FFF + ((v.u >> 16) & 1);   // RNE
  return (unsigned short)(r >> 16);
}

// ---------------- convert kernel: fp32 -> bf16 into ws ----------------
__global__ __launch_bounds__(256) void convert_kern(
    const float* __restrict__ x, const float* __restrict__ w,
    char* __restrict__ ws)
{
  if (blockIdx.x == 0 && threadIdx.x < 64)
    ((float*)(ws + ZP_OFF))[threadIdx.x] = 0.f;   // zero page for OOB lanes

  unsigned short* out = (unsigned short*)ws;
  const int NT8 = (NX + NW) / 8;
  for (int i = blockIdx.x * blockDim.x + threadIdx.x; i < NT8;
       i += gridDim.x * blockDim.x) {
    const int e = i * 8;
    const float* src = (e < NX) ? (x + e) : (w + (e - NX));
    const float4 a = ((const float4*)src)[0];
    const float4 b = ((const float4*)src)[1];
    union { bf16x8 v; unsigned short u[8]; } p;
    p.u[0] = f2bf(a.x); p.u[1] = f2bf(a.y); p.u[2] = f2bf(a.z); p.u[3] = f2bf(a.w);
    p.u[4] = f2bf(b.x); p.u[5] = f2bf(b.y); p.u[6] = f2bf(b.z); p.u[7] = f2bf(b.w);
    *(bf16x8*)(out + e) = p.v;
  }
}

// ------- main GEMM: 256x256, ring-2 counted-vmcnt, 4-phase interleave -------
// Outer skeleton identical to R8 (race-free, no spill). COMPUTE split into
// 4 phases of 16 MFMA each (m201 granularity): per phase ds_read quad ->
// barrier -> setprio(1) MFMA cluster setprio(0) -> barrier. Barrier skew
// overlaps one wave's LDS reads with other waves' MFMA (T3); setprio gets a
// role-split to arbitrate (T5).
__global__ __launch_bounds__(THREADS, 2) void conv_gemm6(
    const char* __restrict__ ws, const float* __restrict__ bias,
    float* __restrict__ out)
{
  __shared__ char lds[2 * SLOT];   // 128 KiB -> 1 block/CU

  const char* xb = ws;
  const char* wb = ws + XB_BYTES;
  const char* zp = ws + ZP_OFF;

  const int tid  = threadIdx.x;
  const int lane = tid & 63;

  // XCD swizzle: grid 392 = 49*8 exactly -> bijective chunked mapping.
  const int bid = blockIdx.x;
  const int m0  = ((bid & 7) * 49 + (bid >> 3)) * 256;

  // ---- staging coords: thread covers rows r0+{0,64,128,192} of A and B
  const int r0  = tid >> 3;                        // 0..63
  const int chk = ((tid & 7) ^ (r0 & 7)) * 16;     // swizzled 16B chunk offset
  const char* zpc = zp + chk;

  int pixA[4], phA[4], pwA[4];
  const char* bsrc[4];
#pragma unroll
  for (int l = 0; l < 4; ++l) {
    const int r  = r0 + l * 64;
    const int p  = m0 + r;
    const int pb = p / 3136;
    const int phw = p - pb * 3136;
    phA[l] = phw / 56;
    pwA[l] = phw - phA[l] * 56;
    pixA[l] = p;
    bsrc[l] = wb + (size_t)r * 2304 + chk;         // w row stride 9*128*2
  }

  // ---- MFMA fragment coords: 8 waves = 2(M) x 4(N); per-wave out 128x64
  const int fr = lane & 15;
  const int fq = lane >> 4;
  const int wv = tid >> 6;
  const int wr = wv >> 2;          // 0..1
  const int wc = wv & 3;           // 0..3

  // ks=1 offset == ks=0 offset ^ 64 (bit-6 identity with the (r&7)<<4 swizzle)
  int aoffs[8], boffs[4];
#pragma unroll
  for (int mi = 0; mi < 8; ++mi) {
    const int r = wr * 128 + mi * 16 + fr;
    aoffs[mi] = r * 128 + ((fq * 16) ^ ((r & 7) << 4));
  }
#pragma unroll
  for (int nj = 0; nj < 4; ++nj) {
    const int c = wc * 64 + nj * 16 + fr;
    boffs[nj] = 32768 + c * 128 + ((fq * 16) ^ ((c & 7) << 4));
  }

  f32x4 acc[8][4];
  const f32x4 zero4 = {0.f, 0.f, 0.f, 0.f};
#pragma unroll
  for (int mi = 0; mi < 8; ++mi)
#pragma unroll
    for (int nj = 0; nj < 4; ++nj) acc[mi][nj] = zero4;

  // 8 global_load_lds per thread per STAGE (4 A + 4 B)
#define STAGE(tt, dst) do {                                                   \
    const int kpos_ = (tt) >> 1, kh_ = (tt) & 1;                              \
    const int ky_ = kpos_ / 3;                                                \
    const int dy_ = ky_ - 1, dx_ = kpos_ - ky_ * 3 - 1;                       \
    _Pragma("unroll")                                                         \
    for (int l = 0; l < 4; ++l) {                                             \
      const int ih_ = phA[l] + dy_, iw_ = pwA[l] + dx_;                       \
      const bool v_ = ((unsigned)ih_ < 56u) & ((unsigned)iw_ < 56u);          \
      const char* ga_ = v_ ? (xb + (size_t)(pixA[l] + dy_ * 56 + dx_) * 256   \
                                 + kh_ * 128 + chk)                           \
                           : zpc;                                             \
      __builtin_amdgcn_global_load_lds((const v_g*)ga_,                       \
          (v_l*)((dst) + l * 8192 + tid * 16), 16, 0, 0);                     \
    }                                                                         \
    _Pragma("unroll")                                                         \
    for (int l = 0; l < 4; ++l)                                               \
      __builtin_amdgcn_global_load_lds((const v_g*)(bsrc[l] + (tt) * 128),    \
          (v_l*)((dst) + 32768 + l * 8192 + tid * 16), 16, 0, 0);             \
  } while (0)

  // one phase: mi-quad mq at K-slice ks; LOADB reloads the B quad (ks entry)
#define PHASE(src, ks, mq, LOADB) do {                                        \
    bf16x8 Aq[4];                                                             \
    _Pragma("unroll")                                                         \
    for (int i = 0; i < 4; ++i)                                               \
      Aq[i] = *(const bf16x8*)((src) + (aoffs[(mq) * 4 + i] ^ ((ks) << 6)));  \
    if (LOADB) {                                                              \
      _Pragma("unroll")                                                       \
      for (int j = 0; j < 4; ++j)                                             \
        Bq[j] = *(const bf16x8*)((src) + (boffs[j] ^ ((ks) << 6)));           \
    }                                                                         \
    __builtin_amdgcn_sched_barrier(0);                                        \
    __builtin_amdgcn_s_barrier();                                             \
    __builtin_amdgcn_sched_barrier(0);                                        \
    __builtin_amdgcn_s_setprio(1);                                            \
    _Pragma("unroll")                                                         \
    for (int i = 0; i < 4; ++i)                                               \
      _Pragma("unroll")                                                       \
      for (int j = 0; j < 4; ++j)                                             \
        acc[(mq) * 4 + i][j] = __builtin_amdgcn_mfma_f32_16x16x32_bf16(       \
            Aq[i], Bq[j], acc[(mq) * 4 + i][j], 0, 0, 0);                     \
    __builtin_amdgcn_s_setprio(0);                                            \
    __builtin_amdgcn_sched_barrier(0);                                        \
    __builtin_amdgcn_s_barrier();                                             \
  } while (0)

#define COMPUTE(src) do {                                                     \
    bf16x8 Bq[4];                                                             \
    PHASE(src, 0, 0, true);                                                   \
    PHASE(src, 0, 1, false);                                                  \
    PHASE(src, 1, 0, true);                                                   \
    PHASE(src, 1, 1, false);                                                  \
  } while (0)

  char* s0 = lds;
  char* s1 = lds + SLOT;

  STAGE(0, s0);

#pragma unroll
  for (int t = 0; t < NT - 1; ++t) {
    // Trailing barrier of tile t-1's last phase == all waves done reading
    // slot (t+1)&1 -> safe to overwrite it now.
    STAGE(t + 1, ((t + 1) & 1) ? s1 : s0);
    // own tile-t loads landed; tile t+1's 8 stay in flight
    asm volatile("s_waitcnt vmcnt(8)" ::: "memory");
    __builtin_amdgcn_s_barrier();          // everyone's tile-t landed
    __builtin_amdgcn_sched_barrier(0);
    COMPUTE((t & 1) ? s1 : s0);
  }

  // final tile: drain
  asm volatile("s_waitcnt vmcnt(0)" ::: "memory");
  __builtin_amdgcn_s_barrier();
  __builtin_amdgcn_sched_barrier(0);
  COMPUTE(((NT - 1) & 1) ? s1 : s0);

#undef STAGE
#undef PHASE
#undef COMPUTE

  // ---- epilogue: + bias, fp32 NHWC ----
  float bv[4];
#pragma unroll
  for (int nj = 0; nj < 4; ++nj) bv[nj] = bias[wc * 64 + nj * 16 + fr];

#pragma unroll
  for (int mi = 0; mi < 8; ++mi) {
#pragma unroll
    for (int j = 0; j < 4; ++j) {
      const int prow = m0 + wr * 128 + mi * 16 + fq * 4 + j;
      float* orow = out + (size_t)prow * OCH + wc * 64 + fr;
#pragma unroll
      for (int nj = 0; nj < 4; ++nj)
        orow[nj * 16] = acc[mi][nj][j] + bv[nj];
    }
  }
}

// ---------------- fallback (round-1 kernel, used if ws too small) ----------------
__global__ __launch_bounds__(256) void conv3x3_mfma_fb(
    const float* __restrict__ x, const float* __restrict__ w,
    const float* __restrict__ bias, float* __restrict__ out)
{
  __shared__ alignas(16) unsigned char As[128 * 64];
  __shared__ alignas(16) unsigned char Bs[128 * 64];

  const int tid = threadIdx.x;
  const int m0 = (blockIdx.x >> 1) * 128;
  const int n0 = (blockIdx.x & 1) * 128;

  const int srow = tid >> 1;
  const int soff = (tid & 1) * 16;

  const int p   = m0 + srow;
  const int pb  = p / (HH * WW_);
  const int phw = p - pb * (HH * WW_);
  const int ph  = phw / WW_;
  const int pw  = phw - ph * WW_;

  const float* xrow = x + ((size_t)((pb * HH + ph) * WW_ + pw)) * CIN + soff;
  const float* wrow = w + (size_t)(n0 + srow) * (9 * CIN) + soff;

  const int sw0 = (srow * 64 + soff * 2)      ^ ((srow & 7) << 4);
  const int sw1 = (srow * 64 + soff * 2 + 16) ^ ((srow & 7) << 4);

  const int lane = tid & 63;
  const int wv = tid >> 6;
  const int wm = (wv >> 1) * 64;
  const int wn = (wv & 1) * 64;
  const int fr = lane & 15;
  const int fq = lane >> 4;

  int aoff[4], boff[4];
#pragma unroll
  for (int i = 0; i < 4; ++i) {
    const int r = wm + i * 16 + fr;
    aoff[i] = (r * 64 + fq * 16) ^ ((r & 7) << 4);
    const int c = wn + i * 16 + fr;
    boff[i] = (c * 64 + fq * 16) ^ ((c & 7) << 4);
  }

  f32x4 acc[4][4];
  const f32x4 zero4 = {0.f, 0.f, 0.f, 0.f};
#pragma unroll
  for (int i = 0; i < 4; ++i)
#pragma unroll
    for (int j = 0; j < 4; ++j) acc[i][j] = zero4;

#pragma unroll 1
  for (int kpos = 0; kpos < 9; ++kpos) {
    const int ky = kpos / 3;
    const int kx = kpos - ky * 3;
    const int ih = ph + ky - 1;
    const int iw = pw + kx - 1;
    const bool valid = ((unsigned)ih < (unsigned)HH) & ((unsigned)iw < (unsigned)WW_);
    const float* asrc = xrow + ((ky - 1) * WW_ + (kx - 1)) * CIN;
    const float* bsrc2 = wrow + kpos * CIN;

#pragma unroll 1
    for (int kc = 0; kc < 4; ++kc) {
      float4 a0, a1, a2, a3;
      if (valid) {
        const float4* s = (const float4*)(asrc + kc * 32);
        a0 = s[0]; a1 = s[1]; a2 = s[2]; a3 = s[3];
      } else {
        a0 = make_float4(0.f, 0.f, 0.f, 0.f);
        a1 = a0; a2 = a0; a3 = a0;
      }
      const float4* tql = (const float4*)(bsrc2 + kc * 32);
      const float4 b0 = tql[0], b1 = tql[1], b2 = tql[2], b3 = tql[3];

      __syncthreads();

      union { bf16x8 v; unsigned short u[8]; } pA0, pA1, pB0, pB1;
      pA0.u[0] = f2bf(a0.x); pA0.u[1] = f2bf(a0.y); pA0.u[2] = f2bf(a0.z); pA0.u[3] = f2bf(a0.w);
      pA0.u[4] = f2bf(a1.x); pA0.u[5] = f2bf(a1.y); pA0.u[6] = f2bf(a1.z); pA0.u[7] = f2bf(a1.w);
      pA1.u[0] = f2bf(a2.x); pA1.u[1] = f2bf(a2.y); pA1.u[2] = f2bf(a2.z); pA1.u[3] = f2bf(a2.w);
      pA1.u[4] = f2bf(a3.x); pA1.u[5] = f2bf(a3.y); pA1.u[6] = f2bf(a3.z); pA1.u[7] = f2bf(a3.w);
      pB0.u[0] = f2bf(b0.x); pB0.u[1] = f2bf(b0.y); pB0.u[2] = f2bf(b0.z); pB0.u[3] = f2bf(b0.w);
      pB0.u[4] = f2bf(b1.x); pB0.u[5] = f2bf(b1.y); pB0.u[6] = f2bf(b1.z); pB0.u[7] = f2bf(b1.w);
      pB1.u[0] = f2bf(b2.x); pB1.u[1] = f2bf(b2.y); pB1.u[2] = f2bf(b2.z); pB1.u[3] = f2bf(b2.w);
      pB1.u[4] = f2bf(b3.x); pB1.u[5] = f2bf(b3.y); pB1.u[6] = f2bf(b3.z); pB1.u[7] = f2bf(b3.w);

      *(bf16x8*)(As + sw0) = pA0.v;
      *(bf16x8*)(As + sw1) = pA1.v;
      *(bf16x8*)(Bs + sw0) = pB0.v;
      *(bf16x8*)(Bs + sw1) = pB1.v;

      __syncthreads();

      bf16x8 af[4], bfr[4];
#pragma unroll
      for (int i = 0; i < 4; ++i) af[i]  = *(const bf16x8*)(As + aoff[i]);
#pragma unroll
      for (int j = 0; j < 4; ++j) bfr[j] = *(const bf16x8*)(Bs + boff[j]);
#pragma unroll
      for (int i = 0; i < 4; ++i)
#pragma unroll
        for (int j = 0; j < 4; ++j)
          acc[i][j] = __builtin_amdgcn_mfma_f32_16x16x32_bf16(af[i], bfr[j], acc[i][j], 0, 0, 0);
    }
  }

  float bv[4];
#pragma unroll
  for (int j = 0; j < 4; ++j) bv[j] = bias[n0 + wn + j * 16 + fr];

#pragma unroll
  for (int mi = 0; mi < 4; ++mi) {
#pragma unroll
    for (int j = 0; j < 4; ++j) {
      const int prow = m0 + wm + mi * 16 + fq * 4 + j;
      float* orow = out + (size_t)prow * OCH + n0 + wn + fr;
#pragma unroll
      for (int ni = 0; ni < 4; ++ni)
        orow[ni * 16] = acc[mi][ni][j] + bv[ni];
    }
  }
}

extern "C" void kernel_launch(void* const* d_in, const int* in_sizes, int n_in,
                              void* d_out, int out_size, void* d_ws, size_t ws_size,
                              hipStream_t stream) {
  (void)in_sizes; (void)n_in; (void)out_size;
  const float* x = (const float*)d_in[0];
  const float* w = (const float*)d_in[1];
  const float* b = (const float*)d_in[2];
  float* out = (float*)d_out;

  if (ws_size >= WS_NEEDED) {
    convert_kern<<<dim3(2048), dim3(256), 0, stream>>>(x, w, (char*)d_ws);
    const int grid = NPIX / 256;   // 392 = 49 * 8 (XCD-swizzle exact)
    conv_gemm6<<<dim3(grid), dim3(THREADS), 0, stream>>>((const char*)d_ws, b, out);
  } else {
    conv3x3_mfma_fb<<<dim3((NPIX / 128) * 2), dim3(256), 0, stream>>>(x, w, b, out);
  }
}

// Round 13
// 203.541 us; speedup vs baseline: 1.0205x; 1.0205x over previous
//
#include <hip/hip_runtime.h>
#include <hip/hip_bf16.h>

#define HH   56
#define WW_  56
#define CIN  128
#define OCH  256
#define NPIX (32*56*56)          // 100352
#define NX   (NPIX*CIN)
#define NW   (OCH*9*CIN)
#define XB_BYTES ((size_t)NX*2)  // 25690112
#define WB_BYTES ((size_t)NW*2)  // 589824
#define ZP_OFF   (XB_BYTES + WB_BYTES)
#define WS_NEEDED (ZP_OFF + 256)

#define NT   18                  // K-tiles of 64 (K = 1152)
#define SLOT 65536               // A 32KB + B 32KB per K-tile (BM=BN=256)
#define THREADS 512

typedef __attribute__((ext_vector_type(8))) short bf16x8;
typedef __attribute__((ext_vector_type(4))) float f32x4;
typedef __attribute__((address_space(1))) void v_g;
typedef __attribute__((address_space(3))) void v_l;

__device__ __forceinline__ unsigned short f2bf(float f) {
  union { float f; unsigned u; } v; v.f = f;
  unsigned r = v.u + 0x7FFF + ((v.u >> 16) & 1);   // RNE
  return (unsigned short)(r >> 16);
}

// ---------------- convert kernel: fp32 -> bf16 into ws ----------------
__global__ __launch_bounds__(256) void convert_kern(
    const float* __restrict__ x, const float* __restrict__ w,
    char* __restrict__ ws)
{
  if (blockIdx.x == 0 && threadIdx.x < 64)
    ((float*)(ws + ZP_OFF))[threadIdx.x] = 0.f;   // zero page for OOB lanes

  unsigned short* out = (unsigned short*)ws;
  const int NT8 = (NX + NW) / 8;
  for (int i = blockIdx.x * blockDim.x + threadIdx.x; i < NT8;
       i += gridDim.x * blockDim.x) {
    const int e = i * 8;
    const float* src = (e < NX) ? (x + e) : (w + (e - NX));
    const float4 a = ((const float4*)src)[0];
    const float4 b = ((const float4*)src)[1];
    union { bf16x8 v; unsigned short u[8]; } p;
    p.u[0] = f2bf(a.x); p.u[1] = f2bf(a.y); p.u[2] = f2bf(a.z); p.u[3] = f2bf(a.w);
    p.u[4] = f2bf(b.x); p.u[5] = f2bf(b.y); p.u[6] = f2bf(b.z); p.u[7] = f2bf(b.w);
    *(bf16x8*)(out + e) = p.v;
  }
}

// --- main GEMM: 256x256 ring-2, 4 phases with LOOKAHEAD ds_reads (T3+T4) ---
// Key change vs R11: each phase issues the NEXT phase's fragment ds_reads
// BEFORE its own MFMA cluster, so the DS pipe works under the MFMA window
// and the compiler's fine-grained lgkmcnt (m97 behavior) replaces full-
// latency waits. G-loads spread 4+4 over ph0/ph1 -> tile-end vmcnt(0) free.
__global__ __launch_bounds__(THREADS, 2) void conv_gemm7(
    const char* __restrict__ ws, const float* __restrict__ bias,
    float* __restrict__ out)
{
  __shared__ char lds[2 * SLOT];   // 128 KiB -> 1 block/CU

  const char* xb = ws;
  const char* wb = ws + XB_BYTES;
  const char* zp = ws + ZP_OFF;

  const int tid  = threadIdx.x;
  const int lane = tid & 63;

  // XCD swizzle: grid 392 = 49*8 exactly -> bijective chunked mapping.
  const int bid = blockIdx.x;
  const int m0  = ((bid & 7) * 49 + (bid >> 3)) * 256;

  // ---- staging coords: thread covers rows r0+{0,64,128,192} of A and B
  const int r0  = tid >> 3;                        // 0..63
  const int chk = ((tid & 7) ^ (r0 & 7)) * 16;     // swizzled 16B chunk offset
  const char* zpc = zp + chk;

  int pixA[4], phA[4], pwA[4];
  const char* bsrc[4];
#pragma unroll
  for (int l = 0; l < 4; ++l) {
    const int r  = r0 + l * 64;
    const int p  = m0 + r;
    const int pb = p / 3136;
    const int phw = p - pb * 3136;
    phA[l] = phw / 56;
    pwA[l] = phw - phA[l] * 56;
    pixA[l] = p;
    bsrc[l] = wb + (size_t)r * 2304 + chk;         // w row stride 9*128*2
  }

  // ---- MFMA fragment coords: 8 waves = 2(M) x 4(N); per-wave out 128x64
  const int fr = lane & 15;
  const int fq = lane >> 4;
  const int wv = tid >> 6;
  const int wr = wv >> 2;          // 0..1
  const int wc = wv & 3;           // 0..3

  // ks=1 offset == ks=0 offset ^ 64 (bit-6 identity with the (r&7)<<4 swizzle)
  int aoffs[8], boffs[4];
#pragma unroll
  for (int mi = 0; mi < 8; ++mi) {
    const int r = wr * 128 + mi * 16 + fr;
    aoffs[mi] = r * 128 + ((fq * 16) ^ ((r & 7) << 4));
  }
#pragma unroll
  for (int nj = 0; nj < 4; ++nj) {
    const int c = wc * 64 + nj * 16 + fr;
    boffs[nj] = 32768 + c * 128 + ((fq * 16) ^ ((c & 7) << 4));
  }

  f32x4 acc[8][4];
  const f32x4 zero4 = {0.f, 0.f, 0.f, 0.f};
#pragma unroll
  for (int mi = 0; mi < 8; ++mi)
#pragma unroll
    for (int nj = 0; nj < 4; ++nj) acc[mi][nj] = zero4;

  // ---- staging macros: full 8-load stage (prologue) and 4-load halves ----
#define STAGE_A2(tt, dst, l0) do {                                            \
    const int kpos_ = (tt) >> 1, kh_ = (tt) & 1;                              \
    const int ky_ = kpos_ / 3;                                                \
    const int dy_ = ky_ - 1, dx_ = kpos_ - ky_ * 3 - 1;                       \
    _Pragma("unroll")                                                         \
    for (int l = (l0); l < (l0) + 2; ++l) {                                   \
      const int ih_ = phA[l] + dy_, iw_ = pwA[l] + dx_;                       \
      const bool v_ = ((unsigned)ih_ < 56u) & ((unsigned)iw_ < 56u);          \
      const char* ga_ = v_ ? (xb + (size_t)(pixA[l] + dy_ * 56 + dx_) * 256   \
                                 + kh_ * 128 + chk)                           \
                           : zpc;                                             \
      __builtin_amdgcn_global_load_lds((const v_g*)ga_,                       \
          (v_l*)((dst) + l * 8192 + tid * 16), 16, 0, 0);                     \
    }                                                                         \
  } while (0)
#define STAGE_B2(tt, dst, l0) do {                                            \
    _Pragma("unroll")                                                         \
    for (int l = (l0); l < (l0) + 2; ++l)                                     \
      __builtin_amdgcn_global_load_lds((const v_g*)(bsrc[l] + (tt) * 128),    \
          (v_l*)((dst) + 32768 + l * 8192 + tid * 16), 16, 0, 0);             \
  } while (0)

#define LDA(dstbuf, src, ks, mq) do {                                         \
    _Pragma("unroll")                                                         \
    for (int i = 0; i < 4; ++i)                                               \
      dstbuf[i] = *(const bf16x8*)((src) + (aoffs[(mq) * 4 + i] ^ ((ks) << 6)));\
  } while (0)
#define LDB(dstbuf, src, ks) do {                                             \
    _Pragma("unroll")                                                         \
    for (int j = 0; j < 4; ++j)                                               \
      dstbuf[j] = *(const bf16x8*)((src) + (boffs[j] ^ ((ks) << 6)));         \
  } while (0)

#define MFMA16(Ab, Bb, q) do {                                                \
    __builtin_amdgcn_s_setprio(1);                                            \
    _Pragma("unroll")                                                         \
    for (int i = 0; i < 4; ++i)                                               \
      _Pragma("unroll")                                                       \
      for (int j = 0; j < 4; ++j)                                             \
        acc[(q) * 4 + i][j] = __builtin_amdgcn_mfma_f32_16x16x32_bf16(        \
            Ab[i], Bb[j], acc[(q) * 4 + i][j], 0, 0, 0);                      \
    __builtin_amdgcn_s_setprio(0);                                            \
  } while (0)

#define SBAR  __builtin_amdgcn_s_barrier()
#define SCHED __builtin_amdgcn_sched_barrier(0)

  char* s0 = lds;
  char* s1 = lds + SLOT;

  // prologue: stage tile 0 fully, then read phase-0 fragments
  STAGE_A2(0, s0, 0); STAGE_A2(0, s0, 2);
  STAGE_B2(0, s0, 0); STAGE_B2(0, s0, 2);
  asm volatile("s_waitcnt vmcnt(0)" ::: "memory");
  SBAR;

  bf16x8 A0[4], A1[4], A2[4], A3[4], B0[4], B1[4];
  LDA(A0, s0, 0, 0);
  LDB(B0, s0, 0);

#pragma unroll
  for (int t = 0; t < NT; ++t) {
    char* src = (t & 1) ? s1 : s0;
    char* nxt = (t & 1) ? s0 : s1;

    // ph0: lookahead A(ks0,mq1); stage half 0 of tile t+1
    LDA(A1, src, 0, 1);
    if (t < NT - 1) { STAGE_A2(t + 1, nxt, 0); STAGE_B2(t + 1, nxt, 0); }
    SCHED; SBAR; SCHED;
    MFMA16(A0, B0, 0);
    SCHED; SBAR;

    // ph1: lookahead A(ks1,mq0) + B(ks1); stage half 1 of tile t+1
    LDA(A2, src, 1, 0);
    LDB(B1, src, 1);
    if (t < NT - 1) { STAGE_A2(t + 1, nxt, 2); STAGE_B2(t + 1, nxt, 2); }
    SCHED; SBAR; SCHED;
    MFMA16(A1, B0, 1);
    SCHED; SBAR;

    // ph2: lookahead A(ks1,mq1)
    LDA(A3, src, 1, 1);
    SCHED; SBAR; SCHED;
    MFMA16(A2, B1, 0);
    SCHED; SBAR;

    // ph3: no lookahead (next slot still landing); drain own stage loads
    SCHED; SBAR; SCHED;
    MFMA16(A3, B1, 1);
    if (t < NT - 1) asm volatile("s_waitcnt vmcnt(0)" ::: "memory");
    SCHED; SBAR;

    // tile-top reads for t+1 (slot nxt now fully landed for all waves)
    if (t < NT - 1) {
      LDA(A0, nxt, 0, 0);
      LDB(B0, nxt, 0);
    }
  }

#undef STAGE_A2
#undef STAGE_B2
#undef LDA
#undef LDB
#undef MFMA16
#undef SBAR
#undef SCHED

  // ---- epilogue: + bias, fp32 NHWC ----
  float bv[4];
#pragma unroll
  for (int nj = 0; nj < 4; ++nj) bv[nj] = bias[wc * 64 + nj * 16 + fr];

#pragma unroll
  for (int mi = 0; mi < 8; ++mi) {
#pragma unroll
    for (int j = 0; j < 4; ++j) {
      const int prow = m0 + wr * 128 + mi * 16 + fq * 4 + j;
      float* orow = out + (size_t)prow * OCH + wc * 64 + fr;
#pragma unroll
      for (int nj = 0; nj < 4; ++nj)
        orow[nj * 16] = acc[mi][nj][j] + bv[nj];
    }
  }
}

// ---------------- fallback (round-1 kernel, used if ws too small) ----------------
__global__ __launch_bounds__(256) void conv3x3_mfma_fb(
    const float* __restrict__ x, const float* __restrict__ w,
    const float* __restrict__ bias, float* __restrict__ out)
{
  __shared__ alignas(16) unsigned char As[128 * 64];
  __shared__ alignas(16) unsigned char Bs[128 * 64];

  const int tid = threadIdx.x;
  const int m0 = (blockIdx.x >> 1) * 128;
  const int n0 = (blockIdx.x & 1) * 128;

  const int srow = tid >> 1;
  const int soff = (tid & 1) * 16;

  const int p   = m0 + srow;
  const int pb  = p / (HH * WW_);
  const int phw = p - pb * (HH * WW_);
  const int ph  = phw / WW_;
  const int pw  = phw - ph * WW_;

  const float* xrow = x + ((size_t)((pb * HH + ph) * WW_ + pw)) * CIN + soff;
  const float* wrow = w + (size_t)(n0 + srow) * (9 * CIN) + soff;

  const int sw0 = (srow * 64 + soff * 2)      ^ ((srow & 7) << 4);
  const int sw1 = (srow * 64 + soff * 2 + 16) ^ ((srow & 7) << 4);

  const int lane = tid & 63;
  const int wv = tid >> 6;
  const int wm = (wv >> 1) * 64;
  const int wn = (wv & 1) * 64;
  const int fr = lane & 15;
  const int fq = lane >> 4;

  int aoff[4], boff[4];
#pragma unroll
  for (int i = 0; i < 4; ++i) {
    const int r = wm + i * 16 + fr;
    aoff[i] = (r * 64 + fq * 16) ^ ((r & 7) << 4);
    const int c = wn + i * 16 + fr;
    boff[i] = (c * 64 + fq * 16) ^ ((c & 7) << 4);
  }

  f32x4 acc[4][4];
  const f32x4 zero4 = {0.f, 0.f, 0.f, 0.f};
#pragma unroll
  for (int i = 0; i < 4; ++i)
#pragma unroll
    for (int j = 0; j < 4; ++j) acc[i][j] = zero4;

#pragma unroll 1
  for (int kpos = 0; kpos < 9; ++kpos) {
    const int ky = kpos / 3;
    const int kx = kpos - ky * 3;
    const int ih = ph + ky - 1;
    const int iw = pw + kx - 1;
    const bool valid = ((unsigned)ih < (unsigned)HH) & ((unsigned)iw < (unsigned)WW_);
    const float* asrc = xrow + ((ky - 1) * WW_ + (kx - 1)) * CIN;
    const float* bsrc2 = wrow + kpos * CIN;

#pragma unroll 1
    for (int kc = 0; kc < 4; ++kc) {
      float4 a0, a1, a2, a3;
      if (valid) {
        const float4* s = (const float4*)(asrc + kc * 32);
        a0 = s[0]; a1 = s[1]; a2 = s[2]; a3 = s[3];
      } else {
        a0 = make_float4(0.f, 0.f, 0.f, 0.f);
        a1 = a0; a2 = a0; a3 = a0;
      }
      const float4* tql = (const float4*)(bsrc2 + kc * 32);
      const float4 b0 = tql[0], b1 = tql[1], b2 = tql[2], b3 = tql[3];

      __syncthreads();

      union { bf16x8 v; unsigned short u[8]; } pA0, pA1, pB0, pB1;
      pA0.u[0] = f2bf(a0.x); pA0.u[1] = f2bf(a0.y); pA0.u[2] = f2bf(a0.z); pA0.u[3] = f2bf(a0.w);
      pA0.u[4] = f2bf(a1.x); pA0.u[5] = f2bf(a1.y); pA0.u[6] = f2bf(a1.z); pA0.u[7] = f2bf(a1.w);
      pA1.u[0] = f2bf(a2.x); pA1.u[1] = f2bf(a2.y); pA1.u[2] = f2bf(a2.z); pA1.u[3] = f2bf(a2.w);
      pA1.u[4] = f2bf(a3.x); pA1.u[5] = f2bf(a3.y); pA1.u[6] = f2bf(a3.z); pA1.u[7] = f2bf(a3.w);
      pB0.u[0] = f2bf(b0.x); pB0.u[1] = f2bf(b0.y); pB0.u[2] = f2bf(b0.z); pB0.u[3] = f2bf(b0.w);
      pB0.u[4] = f2bf(b1.x); pB0.u[5] = f2bf(b1.y); pB0.u[6] = f2bf(b1.z); pB0.u[7] = f2bf(b1.w);
      pB1.u[0] = f2bf(b2.x); pB1.u[1] = f2bf(b2.y); pB1.u[2] = f2bf(b2.z); pB1.u[3] = f2bf(b2.w);
      pB1.u[4] = f2bf(b3.x); pB1.u[5] = f2bf(b3.y); pB1.u[6] = f2bf(b3.z); pB1.u[7] = f2bf(b3.w);

      *(bf16x8*)(As + sw0) = pA0.v;
      *(bf16x8*)(As + sw1) = pA1.v;
      *(bf16x8*)(Bs + sw0) = pB0.v;
      *(bf16x8*)(Bs + sw1) = pB1.v;

      __syncthreads();

      bf16x8 af[4], bfr[4];
#pragma unroll
      for (int i = 0; i < 4; ++i) af[i]  = *(const bf16x8*)(As + aoff[i]);
#pragma unroll
      for (int j = 0; j < 4; ++j) bfr[j] = *(const bf16x8*)(Bs + boff[j]);
#pragma unroll
      for (int i = 0; i < 4; ++i)
#pragma unroll
        for (int j = 0; j < 4; ++j)
          acc[i][j] = __builtin_amdgcn_mfma_f32_16x16x32_bf16(af[i], bfr[j], acc[i][j], 0, 0, 0);
    }
  }

  float bv[4];
#pragma unroll
  for (int j = 0; j < 4; ++j) bv[j] = bias[n0 + wn + j * 16 + fr];

#pragma unroll
  for (int mi = 0; mi < 4; ++mi) {
#pragma unroll
    for (int j = 0; j < 4; ++j) {
      const int prow = m0 + wm + mi * 16 + fq * 4 + j;
      float* orow = out + (size_t)prow * OCH + n0 + wn + fr;
#pragma unroll
      for (int ni = 0; ni < 4; ++ni)
        orow[ni * 16] = acc[mi][ni][j] + bv[ni];
    }
  }
}

extern "C" void kernel_launch(void* const* d_in, const int* in_sizes, int n_in,
                              void* d_out, int out_size, void* d_ws, size_t ws_size,
                              hipStream_t stream) {
  (void)in_sizes; (void)n_in; (void)out_size;
  const float* x = (const float*)d_in[0];
  const float* w = (const float*)d_in[1];
  const float* b = (const float*)d_in[2];
  float* out = (float*)d_out;

  if (ws_size >= WS_NEEDED) {
    convert_kern<<<dim3(2048), dim3(256), 0, stream>>>(x, w, (char*)d_ws);
    const int grid = NPIX / 256;   // 392 = 49 * 8 (XCD-swizzle exact)
    conv_gemm7<<<dim3(grid), dim3(THREADS), 0, stream>>>((const char*)d_ws, b, out);
  } else {
    conv3x3_mfma_fb<<<dim3((NPIX / 128) * 2), dim3(256), 0, stream>>>(x, w, b, out);
  }
}